// Round 5
// baseline (271.406 us; speedup 1.0000x reference)
//
#include <hip/hip_runtime.h>

typedef __attribute__((ext_vector_type(8))) short short8;   // 8 x bf16 (4 VGPR)
typedef __attribute__((ext_vector_type(4))) float f32x4;

#define Bsz 4
#define Cin 256
#define Cout 256
#define Hh 64
#define Ww 64
#define HW 4096
#define NG 16
#define EPSV 1e-5f

#define QP 16     // pixels per block
#define CSTR 40   // col LDS row stride in ushorts: 32 data + 8 pad

static __device__ __forceinline__ unsigned f2bf(float f) {
    unsigned u = __float_as_uint(f);
    return (u + 0x7fffu + ((u >> 16) & 1u)) >> 16;   // RNE bf16
}

static __device__ __forceinline__ float2 ld8(const float* p) {
    float2 v;
    __builtin_memcpy(&v, p, 8);
    return v;
}

// ---------------------------------------------------------------------------
// Kernel 1: weight reorder w[o][c][kk] -> bf16 wtb[ks][o][32],  ks = kk*8 + c/32
// Also zeroes the GN stats accumulators.
// ---------------------------------------------------------------------------
__global__ void wt_kernel(const float* __restrict__ w, ushort* __restrict__ wtb,
                          float* __restrict__ stats) {
    const int i = blockIdx.x * 256 + threadIdx.x;      // over 589824
    if (blockIdx.x == 0 && threadIdx.x < 128) stats[threadIdx.x] = 0.f;
    if (i >= Cout * Cin * 9) return;
    const int o = i / (Cin * 9);
    const int rem = i % (Cin * 9);
    const int c = rem / 9, kk = rem % 9;
    const int ks = kk * 8 + (c >> 5);
    wtb[(ks * 256 + o) * 32 + (c & 31)] = (ushort)f2bf(w[i]);
}

// ---------------------------------------------------------------------------
// Kernel 2: fused deformable sampling + bf16 MFMA conv + GN partial stats.
// Block: 256 threads (4 waves) = 16 pixels x M=256 Co. Grid = 1024 (4 blk/CU).
// Super-step = BK=64 (2 K-chunks, one barrier); 36 super-steps.
// Gathers + A-frags register-prefetched one step ahead (consumed post-MFMA).
// ---------------------------------------------------------------------------
__launch_bounds__(256, 4)
__global__ void dcn_kernel(const float* __restrict__ in,
                           const float* __restrict__ offs,
                           const float* __restrict__ mask,
                           const ushort* __restrict__ wtb,
                           const float* __restrict__ bias,
                           float* __restrict__ out,
                           float* __restrict__ stats) {
    __shared__ int2   s_ta[9 * QP];            // [k][p]: two row base addrs
    __shared__ float4 s_tw[9 * QP];            // [k][p]: folded pair weights
    __shared__ ushort s_col[2][2 * QP * CSTR]; // [buf][kh][px][32+pad]

    const int t  = threadIdx.x;
    const int bx = blockIdx.x;
    // XCD swizzle: XCD (bx&7) -> (batch, h-half); r -> (h-quarter-row, px-quarter)
    const int q  = bx & 7, r = bx >> 3;        // r 0..127
    const int b  = q >> 1;
    const int h  = ((q & 1) << 5) | (r >> 2);
    const int n0 = (r & 3) * QP;               // first pixel of this block
    const int lane = t & 63;
    const int wv   = t >> 6;                   // wave 0..3, m-strip = 64*wv
    const int quad = lane >> 4;
    const int l15  = lane & 15;

    // ---- tap precompute: 9 kernel points x 16 pixels ----
    if (t < 9 * QP) {
        const int k = t / QP, p = t % QP;
        const int wq = n0 + p;
        const float* ob = offs + (size_t)b * 18 * HW + h * Ww + wq;
        const float dy = ob[(2 * k) * HW];
        const float dx = ob[(2 * k + 1) * HW];
        const float m  = mask[((size_t)b * 9 + k) * HW + h * Ww + wq];
        const float y = (float)h + (float)(k / 3 - 1) + dy;
        const float x = (float)wq + (float)(k % 3 - 1) + dx;
        const float y0f = floorf(y), x0f = floorf(x);
        const float ly = y - y0f, lx = x - x0f;
        const float hy = 1.f - ly, hx = 1.f - lx;
        const int y0 = (int)y0f, x0 = (int)x0f;
        const int yc0 = min(max(y0, 0), 63);
        const int yc1 = min(max(y0 + 1, 0), 63);
        const int xb  = min(max(x0, 0), 62);
        float ax = 0.f, ay = 0.f;
        if (x0 == xb) {                       // x0 in [0,62]
            ax = hx; ay = lx;
        } else if (x0 < xb) {                 // x0 < 0
            ax = (x0 + 1 == 0) ? lx : 0.f;
        } else {                              // x0 > 62
            ay = (x0 == 63) ? hx : 0.f;       // x0>=64: both corners OOB
        }
        const float w0 = (y0 >= 0 && y0 < 64) ? m * hy : 0.f;
        const float w1 = (y0 + 1 >= 0 && y0 + 1 < 64) ? m * ly : 0.f;
        s_ta[t] = make_int2(yc0 * 64 + xb, yc1 * 64 + xb);
        s_tw[t] = make_float4(w0 * ax, w0 * ay, w1 * ax, w1 * ay);
    }
    __syncthreads();

    // gather role: thread -> (pixel gn_, channel-group cg of 4 planes)
    const int gn_ = t & 15;
    const int cg  = t >> 4;                    // 0..15 -> ck 4*cg..4*cg+3 of 64
    const int kh_w = cg >> 3, c8 = cg & 7;
    ushort* wslot = &s_col[0][kh_w * (QP * CSTR) + gn_ * CSTR + c8 * 4];
    const int wslot_stride = 2 * QP * CSTR;    // buf stride in ushorts

    f32x4 acc[4];
#pragma unroll
    for (int mt = 0; mt < 4; mt++) acc[mt] = (f32x4){0.f, 0.f, 0.f, 0.f};

    const float* inb = in + (size_t)b * Cin * HW;

    // issue gathers for step s: planes (s/9)*64 + cg*4 + j, tap (s%9)
#define GISSUE(ccq, kk, g)                                                 \
    {                                                                      \
        const int2 ad = s_ta[(kk) * QP + gn_];                             \
        const float* cb = inb + (size_t)((ccq) * 64 + cg * 4) * HW;        \
        _Pragma("unroll")                                                  \
        for (int j = 0; j < 4; j++) {                                      \
            const float* pl = cb + j * HW;                                 \
            g[2 * j]     = ld8(pl + ad.x);                                 \
            g[2 * j + 1] = ld8(pl + ad.y);                                 \
        }                                                                  \
    }

    float2 g[8];
    GISSUE(0, 0, g);                           // prologue: step 0

    int pbuf = 0;
#pragma unroll 1
    for (int s = 0; s < 36; s++) {
        const int ccq = s / 9;
        const int kk  = s - ccq * 9;
        const int ks0 = kk * 8 + ccq * 2;      // weight K-step of kh=0 slab

        // A-frags for THIS step: issue now, consumed after publish+barrier
        short8 afr[4][2];
        {
            const ushort* wp0 = wtb + ((size_t)(ks0 * 256 + wv * 64 + l15)) * 32 + quad * 8;
#pragma unroll
            for (int mt = 0; mt < 4; mt++)
#pragma unroll
                for (int kh = 0; kh < 2; kh++)
                    afr[mt][kh] = *(const short8*)(wp0 + (kh * 256 + mt * 16) * 32);
        }

        // consume prefetched gathers -> publish col slice
        {
            const float4 tw = s_tw[kk * QP + gn_];
            float vv[4];
#pragma unroll
            for (int j = 0; j < 4; j++)
                vv[j] = tw.x * g[2 * j].x + tw.y * g[2 * j].y +
                        tw.z * g[2 * j + 1].x + tw.w * g[2 * j + 1].y;
            const unsigned pk0 = f2bf(vv[0]) | (f2bf(vv[1]) << 16);
            const unsigned pk1 = f2bf(vv[2]) | (f2bf(vv[3]) << 16);
            *(unsigned long long*)(wslot + pbuf * wslot_stride) =
                (unsigned long long)pk0 | ((unsigned long long)pk1 << 32);
        }
        __syncthreads();

        // prefetch gathers for next step (hidden behind MFMA below)
        if (s < 35) {
            const int s1 = s + 1;
            const int ccq1 = s1 / 9;
            GISSUE(ccq1, s1 - ccq1 * 9, g);
        }

        // B-frags from LDS + MFMA
        short8 bfr[2];
#pragma unroll
        for (int kh = 0; kh < 2; kh++)
            bfr[kh] = *(const short8*)&s_col[pbuf][kh * (QP * CSTR) + l15 * CSTR + quad * 8];
#pragma unroll
        for (int mt = 0; mt < 4; mt++) {
            acc[mt] = __builtin_amdgcn_mfma_f32_16x16x32_bf16(afr[mt][0], bfr[0], acc[mt], 0, 0, 0);
            acc[mt] = __builtin_amdgcn_mfma_f32_16x16x32_bf16(afr[mt][1], bfr[1], acc[mt], 0, 0, 0);
        }
        pbuf ^= 1;
    }
#undef GISSUE

    // ---- epilogue: bias, store, GN partial stats (m-tile == GN group) ----
#pragma unroll
    for (int mt = 0; mt < 4; mt++) {
        float sg = 0.f, qg = 0.f;
#pragma unroll
        for (int reg = 0; reg < 4; reg++) {
            const int o = wv * 64 + mt * 16 + quad * 4 + reg;
            const float v = acc[mt][reg] + bias[o];
            out[((size_t)(b * 256 + o)) * HW + h * Ww + n0 + l15] = v;
            sg += v;
            qg += v * v;
        }
#pragma unroll
        for (int off = 32; off; off >>= 1) {
            sg += __shfl_xor(sg, off);
            qg += __shfl_xor(qg, off);
        }
        if (lane == 0) {
            const int grp = wv * 4 + mt;
            atomicAdd(&stats[((size_t)b * NG + grp) * 2],     sg);
            atomicAdd(&stats[((size_t)b * NG + grp) * 2 + 1], qg);
        }
    }
}

// ---------------------------------------------------------------------------
// Kernel 3: GN apply (mu/rsqrt from accumulated sums, in place)
// ---------------------------------------------------------------------------
__global__ void gn_apply_kernel(float* __restrict__ x, const float* __restrict__ stats,
                                const float* __restrict__ gamma,
                                const float* __restrict__ beta) {
    const int i = blockIdx.x * 256 + threadIdx.x;      // float4 idx, 1048576 total
    const int plane = i >> 10;                         // b*256 + o
    const int o = plane & 255;
    const int bg = plane >> 4;                         // b*16 + g
    const float s = stats[bg * 2], qv = stats[bg * 2 + 1];
    const float inv_n = 1.f / 65536.f;
    const float mu = s * inv_n;
    const float var = qv * inv_n - mu * mu;
    const float rs = rsqrtf(var + EPSV);
    const float ga = gamma[o] * rs;
    const float be = beta[o] - mu * ga;
    float4 v = ((float4*)x)[i];
    v.x = v.x * ga + be;
    v.y = v.y * ga + be;
    v.z = v.z * ga + be;
    v.w = v.w * ga + be;
    ((float4*)x)[i] = v;
}

// ---------------------------------------------------------------------------
extern "C" void kernel_launch(void* const* d_in, const int* in_sizes, int n_in,
                              void* d_out, int out_size, void* d_ws, size_t ws_size,
                              hipStream_t stream) {
    const float* input  = (const float*)d_in[0];
    const float* offset = (const float*)d_in[1];
    const float* maskp  = (const float*)d_in[2];
    const float* weight = (const float*)d_in[3];
    const float* bias   = (const float*)d_in[4];
    const float* gamma  = (const float*)d_in[5];
    const float* beta   = (const float*)d_in[6];
    float* out = (float*)d_out;

    ushort* wtb  = (ushort*)d_ws;                           // 1.18 MB
    float* stats = (float*)((char*)d_ws + (size_t)Cout * Cin * 9 * sizeof(ushort));

    hipLaunchKernelGGL(wt_kernel, dim3((Cout * Cin * 9 + 255) / 256), dim3(256), 0,
                       stream, weight, wtb, stats);
    hipLaunchKernelGGL(dcn_kernel, dim3(Bsz * Hh * 4), dim3(256), 0, stream,
                       input, offset, maskp, wtb, bias, out, stats);
    hipLaunchKernelGGL(gn_apply_kernel, dim3((Bsz * Cout * HW / 4) / 256), dim3(256), 0,
                       stream, out, stats, gamma, beta);
}